// Round 5
// baseline (406.045 us; speedup 1.0000x reference)
//
#include <hip/hip_runtime.h>
#include <math.h>

// Problem constants: N=100000, K=10, T=7, D=7, O=32
#define T_ 7
#define D_ 7
#define K_ 10
#define O_ 32
#define NREP 16
#define NEG_SLOPE 0.01f

typedef float vf4 __attribute__((ext_vector_type(4)));  // clang-native: ok for nontemporal builtin

// ---------------- K0: zero the replicated output accumulators --------------
__global__ void k0_zero(float* __restrict__ acc) {
    int i = threadIdx.x;
    if (i < NREP * O_) acc[i] = 0.f;
}

// ---------------- K1: per-(t, node-block) aggregation ----------------------
// Grid = (ceil(N/64), T_), ONE WAVE per block -> 7x the wave count of the
// fused kernel (the R0-R3 invariant: delivered BW scaled linearly with
// resident waves/CU; the grid was starving the machine at 6.1 waves/CU).
// Each lane owns one node at one t: 18 non-temporal float4 loads from a
// 16B-aligned window (row is only 8B-aligned when n is odd; load the
// enclosing aligned 72 floats and select-shift by 2), then 10 neighbor
// micro-GEMVs, masked-mean, coalesced stores to ws[(t*7+o)*N + n].
__global__ __launch_bounds__(64) void k1_agg(
    const float* __restrict__ xhet,   // [T,N,K,D]
    const float* __restrict__ Wc,     // [T,D,D]
    const float* __restrict__ bc,     // [T,D]
    float* __restrict__ ws,           // [49][N] aggregate features
    int N)
{
    const int t  = blockIdx.y;
    const int tx = threadIdx.x;
    const int n  = blockIdx.x * 64 + tx;
    const bool active = (n < N);
    const int nc = active ? n : (N - 1);

    // block-uniform weights -> scalar regs
    float w[D_][D_], bias[D_];
    #pragma unroll
    for (int o = 0; o < D_; ++o) {
        bias[o] = bc[t * D_ + o];
        #pragma unroll
        for (int d = 0; d < D_; ++d) w[o][d] = Wc[(t * D_ + o) * D_ + d];
    }

    // aligned-window load: idx = row start (float units), base = idx & ~3.
    // off = idx & 3 is 0 or 2 (idx = nc*70 + t*N*70, both terms even).
    // base+72 never exceeds the tensor: the last row (t=6, nc=N-1) has off=2
    // so base+72 == idx+70 == end exactly; off=0 rows read 2 floats into the
    // next row, in-bounds.
    const size_t idx  = ((size_t)t * N + nc) * 70;
    const size_t base = idx & ~(size_t)3;
    const bool   sh   = (idx & 3) != 0;

    const vf4* r4 = (const vf4*)(xhet + base);
    float f[72];
    #pragma unroll
    for (int j = 0; j < 18; ++j) {
        vf4 v = __builtin_nontemporal_load(r4 + j);
        f[4*j+0] = v.x; f[4*j+1] = v.y; f[4*j+2] = v.z; f[4*j+3] = v.w;
    }

    float acc[D_] = {0.f, 0.f, 0.f, 0.f, 0.f, 0.f, 0.f};
    float cnt = 0.f;
    #pragma unroll
    for (int kk = 0; kk < K_ / 2; ++kk) {      // 2 neighbors per chunk
        float g[14];
        #pragma unroll
        for (int j = 0; j < 14; ++j)            // static indices only (max 71)
            g[j] = sh ? f[kk*14 + j + 2] : f[kk*14 + j];
        #pragma unroll
        for (int hh = 0; hh < 2; ++hh) {
            float pre[D_];
            #pragma unroll
            for (int o = 0; o < D_; ++o) pre[o] = bias[o];
            #pragma unroll
            for (int d = 0; d < D_; ++d) {
                const float xv = g[hh * 7 + d];
                #pragma unroll
                for (int o = 0; o < D_; ++o) pre[o] = fmaf(xv, w[o][d], pre[o]);
            }
            bool nz = false;
            #pragma unroll
            for (int o = 0; o < D_; ++o) nz = nz || (pre[o] != 0.f);
            cnt += nz ? 1.f : 0.f;
            #pragma unroll
            for (int o = 0; o < D_; ++o)
                acc[o] += (pre[o] >= 0.f) ? pre[o] : NEG_SLOPE * pre[o];
        }
    }
    const float inv = 1.f / fmaxf(cnt, 1.f);
    if (active) {
        #pragma unroll
        for (int o = 0; o < D_; ++o)
            ws[(size_t)(t * D_ + o) * N + n] = acc[o] * inv;   // coalesced
    }
}

// ---------------- K2: epilogue ---------------------------------------------
// One thread per node. Coalesced column reads of ws, self-embedding via
// all-7-candidates + select (weights are uniform scalar loads, no gather),
// 56->32 GEMV + sigmoid, wave reduce, replicated atomics.
__global__ __launch_bounds__(256) void k2_out(
    const float* __restrict__ ws,     // [49][N]
    const float* __restrict__ xnode,  // [N,D]
    const int*   __restrict__ types,  // [N]
    const float* __restrict__ Wc,     // [T,D,D]
    const float* __restrict__ bc,     // [T,D]
    const float* __restrict__ Wagg,   // [O,56]
    const float* __restrict__ bagg,   // [O]
    float* __restrict__ acc_out,      // [NREP][O]
    int N)
{
    const int tx = threadIdx.x;
    const int n  = blockIdx.x * 256 + tx;
    const bool active = (n < N);
    const int nc = active ? n : (N - 1);

    float het[49];                     // independent loads -> deep ILP
    #pragma unroll
    for (int j = 0; j < 49; ++j) het[j] = ws[(size_t)j * N + nc];

    const int tp = types[nc];
    float x[D_];
    #pragma unroll
    for (int d = 0; d < D_; ++d) x[d] = xnode[(size_t)nc * D_ + d];

    float self[D_] = {0.f, 0.f, 0.f, 0.f, 0.f, 0.f, 0.f};
    for (int t = 0; t < T_; ++t) {     // uniform weight loads per t
        #pragma unroll
        for (int o = 0; o < D_; ++o) {
            float p = bc[t * D_ + o];
            #pragma unroll
            for (int d = 0; d < D_; ++d) p = fmaf(x[d], Wc[(t * D_ + o) * D_ + d], p);
            p = (p >= 0.f) ? p : NEG_SLOPE * p;
            self[o] = (tp == t) ? p : self[o];
        }
    }

    const int wv = tx >> 6, lane = tx & 63;
    #pragma unroll 4                    // 4 concurrent dot-product chains
    for (int o = 0; o < O_; ++o) {
        float s = bagg[o];
        const float* wr = Wagg + o * 56;     // uniform -> scalar loads
        #pragma unroll
        for (int j = 0; j < 49; ++j) s = fmaf(het[j], wr[j], s);
        #pragma unroll
        for (int d = 0; d < D_; ++d) s = fmaf(self[d], wr[49 + d], s);
        float val = active ? 1.f / (1.f + __expf(-s)) : 0.f;
        #pragma unroll
        for (int off = 32; off >= 1; off >>= 1) val += __shfl_down(val, off);
        if (lane == 0)
            atomicAdd(acc_out + ((blockIdx.x * 4 + wv) & (NREP - 1)) * O_ + o, val);
    }
}

// ---------------- K3: sum replicas, divide by N into d_out -----------------
__global__ void k3_finish(const float* __restrict__ acc, float* __restrict__ out, float invN) {
    int o = threadIdx.x;
    if (o < O_) {
        float s = 0.f;
        #pragma unroll
        for (int rr = 0; rr < NREP; ++rr) s += acc[rr * O_ + o];
        out[o] = s * invN;
    }
}

// ---------------- fallback: R3 single fused kernel (if ws too small) -------
__global__ __launch_bounds__(64) void k_fused_fb(
    const float* __restrict__ xhet, const float* __restrict__ xnode,
    const int* __restrict__ types, const float* __restrict__ Wc,
    const float* __restrict__ bc, const float* __restrict__ Wagg,
    const float* __restrict__ bagg, float* __restrict__ acc_out, int N)
{
    const int tx = threadIdx.x;
    const int n = blockIdx.x * 64 + tx;
    const bool active = (n < N);
    const int nc = active ? n : (N - 1);
    const int tp = types[nc];
    float x[D_];
    #pragma unroll
    for (int d = 0; d < D_; ++d) x[d] = xnode[(size_t)nc * D_ + d];
    float h[(T_ + 1) * D_];
    #pragma unroll
    for (int j = 0; j < (T_ + 1) * D_; ++j) h[j] = 0.f;
    for (int t = 0; t < T_; ++t) {
        float w[D_][D_], bias[D_];
        #pragma unroll
        for (int o = 0; o < D_; ++o) {
            bias[o] = bc[t * D_ + o];
            #pragma unroll
            for (int d = 0; d < D_; ++d) w[o][d] = Wc[(t * D_ + o) * D_ + d];
        }
        const float* row = xhet + ((size_t)t * N + nc) * 70;
        float acc[D_] = {0.f,0.f,0.f,0.f,0.f,0.f,0.f};
        float cnt = 0.f;
        #pragma unroll
        for (int kk = 0; kk < K_ / 2; ++kk) {
            float f[14];
            const float2* p2 = (const float2*)(row + kk * 14);
            #pragma unroll
            for (int j2 = 0; j2 < 7; ++j2) { float2 v = p2[j2]; f[2*j2] = v.x; f[2*j2+1] = v.y; }
            #pragma unroll
            for (int hh = 0; hh < 2; ++hh) {
                float pre[D_];
                #pragma unroll
                for (int o = 0; o < D_; ++o) pre[o] = bias[o];
                #pragma unroll
                for (int d = 0; d < D_; ++d) {
                    const float xv = f[hh * 7 + d];
                    #pragma unroll
                    for (int o = 0; o < D_; ++o) pre[o] = fmaf(xv, w[o][d], pre[o]);
                }
                bool nz = false;
                #pragma unroll
                for (int o = 0; o < D_; ++o) nz = nz || (pre[o] != 0.f);
                cnt += nz ? 1.f : 0.f;
                #pragma unroll
                for (int o = 0; o < D_; ++o)
                    acc[o] += (pre[o] >= 0.f) ? pre[o] : NEG_SLOPE * pre[o];
            }
        }
        const float inv = 1.f / fmaxf(cnt, 1.f);
        #pragma unroll
        for (int o = 0; o < D_; ++o) h[t * D_ + o] = acc[o] * inv;
        float ps[D_];
        #pragma unroll
        for (int o = 0; o < D_; ++o) {
            float p = bias[o];
            #pragma unroll
            for (int d = 0; d < D_; ++d) p = fmaf(x[d], w[o][d], p);
            ps[o] = (p >= 0.f) ? p : NEG_SLOPE * p;
        }
        if (tp == t) {
            #pragma unroll
            for (int o = 0; o < D_; ++o) h[T_ * D_ + o] = ps[o];
        }
    }
    #pragma unroll 4
    for (int o = 0; o < O_; ++o) {
        float s = bagg[o];
        const float4* wrow = (const float4*)(Wagg + o * 56);
        #pragma unroll
        for (int q = 0; q < 14; ++q) {
            float4 w4 = wrow[q];
            s += h[4*q] * w4.x + h[4*q+1] * w4.y + h[4*q+2] * w4.z + h[4*q+3] * w4.w;
        }
        float val = active ? 1.f / (1.f + __expf(-s)) : 0.f;
        #pragma unroll
        for (int off = 32; off >= 1; off >>= 1) val += __shfl_down(val, off);
        if (tx == 0) atomicAdd(acc_out + (blockIdx.x & (NREP - 1)) * O_ + o, val);
    }
}

extern "C" void kernel_launch(void* const* d_in, const int* in_sizes, int n_in,
                              void* d_out, int out_size, void* d_ws, size_t ws_size,
                              hipStream_t stream) {
    const float* xnode = (const float*)d_in[0];   // [N,D]
    const float* xhet  = (const float*)d_in[1];   // [T,N,K,D]
    const int*   types = (const int*)d_in[2];     // [N]
    const float* Wc    = (const float*)d_in[3];   // [T,D,D]
    const float* bc    = (const float*)d_in[4];   // [T,D]
    const float* Wagg  = (const float*)d_in[5];   // [O,56]
    const float* bagg  = (const float*)d_in[6];   // [O]
    float* out = (float*)d_out;

    const int N = in_sizes[2];
    float* acc_out = (float*)d_ws;                          // NREP*32 floats
    float* ws_h    = (float*)d_ws + NREP * O_;              // [49][N]
    const size_t need = ((size_t)NREP * O_ + (size_t)49 * N) * sizeof(float);

    const int nblk64 = (N + 63) / 64;

    k0_zero<<<1, 512, 0, stream>>>(acc_out);
    if (ws_size >= need) {
        dim3 g1(nblk64, T_);
        k1_agg<<<g1, 64, 0, stream>>>(xhet, Wc, bc, ws_h, N);
        const int nblk256 = (N + 255) / 256;
        k2_out<<<nblk256, 256, 0, stream>>>(ws_h, xnode, types, Wc, bc, Wagg, bagg, acc_out, N);
    } else {
        k_fused_fb<<<nblk64, 64, 0, stream>>>(xhet, xnode, types, Wc, bc, Wagg, bagg, acc_out, N);
    }
    k3_finish<<<1, 64, 0, stream>>>(acc_out, out, 1.f / (float)N);
}

// Round 7
// 398.210 us; speedup vs baseline: 1.0197x; 1.0197x over previous
//
#include <hip/hip_runtime.h>
#include <math.h>

// Problem constants: N=100000, K=10, T=7, D=7, O=32
#define T_ 7
#define D_ 7
#define K_ 10
#define O_ 32
#define NREP 64
#define NEG_SLOPE 0.01f

// ---------------- K0: zero the replicated output accumulators --------------
__global__ void k0_zero(float* __restrict__ acc) {
    for (int i = threadIdx.x; i < NREP * O_; i += 256) acc[i] = 0.f;
}

// ---------------- K1: coalesced-VMEM aggregation ---------------------------
// The discriminating experiment: R0-R5 pinned to-core BW at ~1.6 TB/s with
// either the DMA path (coalesced) or plain VMEM with per-lane 280B-stride
// (uncoalesced: 64 lines per instruction). m13's coalesced-VMEM pattern is
// the untested cell (6.3 TB/s). Here: one wave = (t, 32 nodes); the wave's
// 8960B window is staged with 18 COALESCED float2 loads (lane->consecutive
// addresses) into a LINEAR LDS tile (LDS layout == global layout, no remap),
// then per-lane strided ds_read_b32 rows (stride 70 floats -> 2-way bank
// aliasing, free per m136). Lanes: i=l&31 node, half=l>>5 takes neighbors
// k in [5*half, 5*half+5); pair-reduce via shfl_xor(32).
__global__ __launch_bounds__(64) void k1_agg(
    const float* __restrict__ xhet,   // [T,N,K,D]
    const float* __restrict__ Wc,     // [T,D,D]
    const float* __restrict__ bc,     // [T,D]
    float* __restrict__ ws,           // [49][N]
    int N)
{
    __shared__ __align__(16) float tile[32 * 70];   // 8960 B -> 16 wg/CU

    const int t  = blockIdx.y;
    const int l  = threadIdx.x;
    const int i    = l & 31;
    const int half = l >> 5;
    const int nodeBase = blockIdx.x * 32;

    // block-uniform weights -> scalar regs
    float w[D_][D_], bias[D_];
    #pragma unroll
    for (int o = 0; o < D_; ++o) {
        bias[o] = bc[t * D_ + o];
        #pragma unroll
        for (int d = 0; d < D_; ++d) w[o][d] = Wc[(t * D_ + o) * D_ + d];
    }

    // ---- coalesced window copy: 2240 floats = 1120 float2, 18 rounds.
    // float2 never crosses a 70-float row (even offsets), window start is
    // 8B-aligned ((t*N+nodeBase)*70 even).
    const int nvalid = min(32, N - nodeBase);
    const int L2v = nvalid * 35;                      // float2 count
    const float2* g2 = (const float2*)(xhet + ((size_t)t * N + nodeBase) * 70);
    float2* t2 = (float2*)tile;
    #pragma unroll
    for (int j = 0; j < 18; ++j) {
        const int idx = j * 64 + l;
        if (idx < L2v) t2[idx] = g2[idx];
    }
    // single wave: all DS writes retired -> tile visible to every lane
    asm volatile("s_waitcnt lgkmcnt(0)" ::: "memory");

    // ---- per-lane row slice: 35 floats (5 neighbors x 7)
    const float* row = tile + i * 70 + half * 35;
    float f[35];
    #pragma unroll
    for (int e = 0; e < 35; ++e) f[e] = row[e];

    float acc[D_] = {0.f, 0.f, 0.f, 0.f, 0.f, 0.f, 0.f};
    float cnt = 0.f;
    #pragma unroll
    for (int m = 0; m < 5; ++m) {
        float pre[D_];
        #pragma unroll
        for (int o = 0; o < D_; ++o) pre[o] = bias[o];
        #pragma unroll
        for (int d = 0; d < D_; ++d) {
            const float xv = f[7 * m + d];
            #pragma unroll
            for (int o = 0; o < D_; ++o) pre[o] = fmaf(xv, w[o][d], pre[o]);
        }
        bool nz = false;
        #pragma unroll
        for (int o = 0; o < D_; ++o) nz = nz || (pre[o] != 0.f);
        cnt += nz ? 1.f : 0.f;
        #pragma unroll
        for (int o = 0; o < D_; ++o)
            acc[o] += (pre[o] >= 0.f) ? pre[o] : NEG_SLOPE * pre[o];
    }
    // pair-reduce across halves (lane i <-> i+32)
    #pragma unroll
    for (int o = 0; o < D_; ++o) acc[o] += __shfl_xor(acc[o], 32);
    cnt += __shfl_xor(cnt, 32);
    const float inv = 1.f / fmaxf(cnt, 1.f);

    if (half == 0 && i < nvalid) {
        #pragma unroll
        for (int o = 0; o < D_; ++o)
            ws[(size_t)(t * D_ + o) * N + nodeBase + i] = acc[o] * inv;
    }
}

// ---------------- K2: epilogue, 4 threads per node -------------------------
// sub = g&3 handles outputs o = sub*8 .. sub*8+7. 24 waves/CU (vs 6 before),
// per-thread GEMV work /4. het loads coalesced (16 nodes x 4 subs per wave
// = one 64B line per j). Reduce over the 16 node-slots via shfl_down
// offsets 32/16/8/4 (sub-class preserved); lanes 0..3 do the atomics.
__global__ __launch_bounds__(256) void k2_out(
    const float* __restrict__ ws,     // [49][N]
    const float* __restrict__ xnode,  // [N,D]
    const int*   __restrict__ types,  // [N]
    const float* __restrict__ Wc,     // [T,D,D]
    const float* __restrict__ bc,     // [T,D]
    const float* __restrict__ Wagg,   // [O,56]
    const float* __restrict__ bagg,   // [O]
    float* __restrict__ acc_out,      // [NREP][O]
    int N)
{
    const int tx = threadIdx.x;
    const int g  = blockIdx.x * 256 + tx;
    const int node = g >> 2, sub = g & 3;
    const bool active = (node < N);
    const int nc = active ? node : (N - 1);

    float het[49];
    #pragma unroll
    for (int j = 0; j < 49; ++j) het[j] = ws[(size_t)j * N + nc];

    const int tp = types[nc];
    float x[D_];
    #pragma unroll
    for (int d = 0; d < D_; ++d) x[d] = xnode[(size_t)nc * D_ + d];

    float self[D_] = {0.f, 0.f, 0.f, 0.f, 0.f, 0.f, 0.f};
    for (int t = 0; t < T_; ++t) {
        #pragma unroll
        for (int o = 0; o < D_; ++o) {
            float p = bc[t * D_ + o];
            #pragma unroll
            for (int d = 0; d < D_; ++d) p = fmaf(x[d], Wc[(t * D_ + o) * D_ + d], p);
            p = (p >= 0.f) ? p : NEG_SLOPE * p;
            self[o] = (tp == t) ? p : self[o];
        }
    }

    const int lane = tx & 63;
    float vals[8];
    #pragma unroll
    for (int q = 0; q < 8; ++q) {
        const int o = sub * 8 + q;
        float s = bagg[o];
        const float* wr = Wagg + o * 56;
        #pragma unroll
        for (int j = 0; j < 49; ++j) s = fmaf(het[j], wr[j], s);
        #pragma unroll
        for (int d = 0; d < D_; ++d) s = fmaf(self[d], wr[49 + d], s);
        float v = active ? 1.f / (1.f + __expf(-s)) : 0.f;
        #pragma unroll
        for (int off = 32; off >= 4; off >>= 1) v += __shfl_down(v, off);
        vals[q] = v;
    }
    if (lane < 4) {   // lane == sub for lanes 0..3
        const int rep = blockIdx.x & (NREP - 1);
        #pragma unroll
        for (int q = 0; q < 8; ++q)
            atomicAdd(acc_out + rep * O_ + lane * 8 + q, vals[q]);
    }
}

// ---------------- K3: sum replicas, divide by N into d_out -----------------
__global__ void k3_finish(const float* __restrict__ acc, float* __restrict__ out, float invN) {
    int o = threadIdx.x;
    if (o < O_) {
        float s = 0.f;
        #pragma unroll
        for (int rr = 0; rr < NREP; ++rr) s += acc[rr * O_ + o];
        out[o] = s * invN;
    }
}

// ---------------- fallback: R3 single fused kernel (if ws too small) -------
__global__ __launch_bounds__(64) void k_fused_fb(
    const float* __restrict__ xhet, const float* __restrict__ xnode,
    const int* __restrict__ types, const float* __restrict__ Wc,
    const float* __restrict__ bc, const float* __restrict__ Wagg,
    const float* __restrict__ bagg, float* __restrict__ acc_out, int N)
{
    const int tx = threadIdx.x;
    const int n = blockIdx.x * 64 + tx;
    const bool active = (n < N);
    const int nc = active ? n : (N - 1);
    const int tp = types[nc];
    float x[D_];
    #pragma unroll
    for (int d = 0; d < D_; ++d) x[d] = xnode[(size_t)nc * D_ + d];
    float h[(T_ + 1) * D_];
    #pragma unroll
    for (int j = 0; j < (T_ + 1) * D_; ++j) h[j] = 0.f;
    for (int t = 0; t < T_; ++t) {
        float w[D_][D_], bias[D_];
        #pragma unroll
        for (int o = 0; o < D_; ++o) {
            bias[o] = bc[t * D_ + o];
            #pragma unroll
            for (int d = 0; d < D_; ++d) w[o][d] = Wc[(t * D_ + o) * D_ + d];
        }
        const float* row = xhet + ((size_t)t * N + nc) * 70;
        float acc[D_] = {0.f,0.f,0.f,0.f,0.f,0.f,0.f};
        float cnt = 0.f;
        #pragma unroll
        for (int kk = 0; kk < K_ / 2; ++kk) {
            float f[14];
            const float2* p2 = (const float2*)(row + kk * 14);
            #pragma unroll
            for (int j2 = 0; j2 < 7; ++j2) { float2 v = p2[j2]; f[2*j2] = v.x; f[2*j2+1] = v.y; }
            #pragma unroll
            for (int hh = 0; hh < 2; ++hh) {
                float pre[D_];
                #pragma unroll
                for (int o = 0; o < D_; ++o) pre[o] = bias[o];
                #pragma unroll
                for (int d = 0; d < D_; ++d) {
                    const float xv = f[hh * 7 + d];
                    #pragma unroll
                    for (int o = 0; o < D_; ++o) pre[o] = fmaf(xv, w[o][d], pre[o]);
                }
                bool nz = false;
                #pragma unroll
                for (int o = 0; o < D_; ++o) nz = nz || (pre[o] != 0.f);
                cnt += nz ? 1.f : 0.f;
                #pragma unroll
                for (int o = 0; o < D_; ++o)
                    acc[o] += (pre[o] >= 0.f) ? pre[o] : NEG_SLOPE * pre[o];
            }
        }
        const float inv = 1.f / fmaxf(cnt, 1.f);
        #pragma unroll
        for (int o = 0; o < D_; ++o) h[t * D_ + o] = acc[o] * inv;
        float ps[D_];
        #pragma unroll
        for (int o = 0; o < D_; ++o) {
            float p = bias[o];
            #pragma unroll
            for (int d = 0; d < D_; ++d) p = fmaf(x[d], w[o][d], p);
            ps[o] = (p >= 0.f) ? p : NEG_SLOPE * p;
        }
        if (tp == t) {
            #pragma unroll
            for (int o = 0; o < D_; ++o) h[T_ * D_ + o] = ps[o];
        }
    }
    #pragma unroll 4
    for (int o = 0; o < O_; ++o) {
        float s = bagg[o];
        const float4* wrow = (const float4*)(Wagg + o * 56);
        #pragma unroll
        for (int q = 0; q < 14; ++q) {
            float4 w4 = wrow[q];
            s += h[4*q] * w4.x + h[4*q+1] * w4.y + h[4*q+2] * w4.z + h[4*q+3] * w4.w;
        }
        float val = active ? 1.f / (1.f + __expf(-s)) : 0.f;
        #pragma unroll
        for (int off = 32; off >= 1; off >>= 1) val += __shfl_down(val, off);
        if (tx == 0) atomicAdd(acc_out + (blockIdx.x & (NREP - 1)) * O_ + o, val);
    }
}

extern "C" void kernel_launch(void* const* d_in, const int* in_sizes, int n_in,
                              void* d_out, int out_size, void* d_ws, size_t ws_size,
                              hipStream_t stream) {
    const float* xnode = (const float*)d_in[0];   // [N,D]
    const float* xhet  = (const float*)d_in[1];   // [T,N,K,D]
    const int*   types = (const int*)d_in[2];     // [N]
    const float* Wc    = (const float*)d_in[3];   // [T,D,D]
    const float* bc    = (const float*)d_in[4];   // [T,D]
    const float* Wagg  = (const float*)d_in[5];   // [O,56]
    const float* bagg  = (const float*)d_in[6];   // [O]
    float* out = (float*)d_out;

    const int N = in_sizes[2];
    float* acc_out = (float*)d_ws;                          // NREP*32 floats
    float* ws_h    = (float*)d_ws + NREP * O_;              // [49][N]
    const size_t need = ((size_t)NREP * O_ + (size_t)49 * N) * sizeof(float);

    k0_zero<<<1, 256, 0, stream>>>(acc_out);
    if (ws_size >= need) {
        const int nblk32 = (N + 31) / 32;                   // 3125 @ N=100000 (exact)
        dim3 g1(nblk32, T_);
        k1_agg<<<g1, 64, 0, stream>>>(xhet, Wc, bc, ws_h, N);
        const int nblk = (4 * N + 255) / 256;               // 4 threads per node
        k2_out<<<nblk, 256, 0, stream>>>(ws_h, xnode, types, Wc, bc, Wagg, bagg, acc_out, N);
    } else {
        const int nblk64 = (N + 63) / 64;
        k_fused_fb<<<nblk64, 64, 0, stream>>>(xhet, xnode, types, Wc, bc, Wagg, bagg, acc_out, N);
    }
    k3_finish<<<1, 64, 0, stream>>>(acc_out, out, 1.f / (float)N);
}

// Round 8
// 390.754 us; speedup vs baseline: 1.0391x; 1.0191x over previous
//
#include <hip/hip_runtime.h>
#include <math.h>

// Problem constants: N=100000, K=10, T=7, D=7, O=32
#define T_ 7
#define D_ 7
#define K_ 10
#define O_ 32
#define NPB 64            // one wave per workgroup
#define NREP 16
#define NEG_SLOPE 0.01f

typedef float vf4 __attribute__((ext_vector_type(4)));

// ---------------- K0: zero the replicated output accumulators --------------
__global__ void k0_zero(float* __restrict__ acc) {
    int i = threadIdx.x;
    if (i < NREP * O_) acc[i] = 0.f;
}

// ---------------- fused kernel, system-scope loads -------------------------
// R0-R7 pinned to-core read BW at ~1.6-1.7 TB/s across DMA/VMEM,
// coalesced/strided, 4.5-14 waves/CU, drain/pipelined -- while the harness
// fill WRITES at 6.8 TB/s. Remaining untested mechanism: the L2/L3
// allocation path on reads. This round: identical R3 fused structure, loads
// swapped for inline-asm global_load_dwordx4 with sc0 sc1 (system scope,
// skips low-level cache allocation on gfx94x+). Aligned-window trick: row
// start is 8B-aligned (idx even), so load the enclosing 16B-aligned 72
// floats and statically select-shift by (idx&3)==2.
__global__ __launch_bounds__(NPB) void k_fused(
    const float* __restrict__ xhet,   // [T,N,K,D]
    const float* __restrict__ xnode,  // [N,D]
    const int*   __restrict__ types,  // [N]
    const float* __restrict__ Wc,     // [T,D,D]
    const float* __restrict__ bc,     // [T,D]
    const float* __restrict__ Wagg,   // [O,56]
    const float* __restrict__ bagg,   // [O]
    float* __restrict__ acc_out,      // [NREP][O]
    int N)
{
    const int tx = threadIdx.x;
    const int n = blockIdx.x * NPB + tx;
    const bool active = (n < N);
    const int nc = active ? n : (N - 1);   // clamp; zeroed at epilogue reduce

    const int tp = types[nc];
    float x[D_];
    #pragma unroll
    for (int d = 0; d < D_; ++d) x[d] = xnode[(size_t)nc * D_ + d];

    float h[(T_ + 1) * D_];            // concat layout: h[t*7+o], self at 49..55
    #pragma unroll
    for (int j = 0; j < (T_ + 1) * D_; ++j) h[j] = 0.f;

    for (int t = 0; t < T_; ++t) {
        // block-uniform weights -> scalar regs
        float w[D_][D_], bias[D_];
        #pragma unroll
        for (int o = 0; o < D_; ++o) {
            bias[o] = bc[t * D_ + o];
            #pragma unroll
            for (int d = 0; d < D_; ++d) w[o][d] = Wc[(t * D_ + o) * D_ + d];
        }

        // aligned 72-float window enclosing this lane's 70-float row.
        // idx even => off in {0,2}; base+72 stays in-bounds (last row t=6,
        // nc=N-1 has off=2 so base+72 == end exactly; off=0 reads 2 floats
        // of the next row, in-bounds).
        const size_t idx  = ((size_t)t * N + nc) * 70;
        const size_t base = idx & ~(size_t)3;
        const bool   sh   = (idx & 3) != 0;
        const float* bp   = xhet + base;

        // ---- 18 system-scope 16B loads (sc0 sc1), issued back-to-back.
        vf4 f4[18];
        #pragma unroll
        for (int j = 0; j < 18; ++j) {
            asm volatile("global_load_dwordx4 %0, %1, off sc0 sc1"
                         : "=v"(f4[j]) : "v"(bp + 4 * j) : "memory");
        }
        asm volatile("s_waitcnt vmcnt(0)" ::: "memory");
        __builtin_amdgcn_sched_barrier(0);   // rule #18: pin uses after the wait

        float f[72];
        #pragma unroll
        for (int j = 0; j < 18; ++j) {
            f[4*j+0] = f4[j].x; f[4*j+1] = f4[j].y;
            f[4*j+2] = f4[j].z; f[4*j+3] = f4[j].w;
        }

        float acc[D_] = {0.f, 0.f, 0.f, 0.f, 0.f, 0.f, 0.f};
        float cnt = 0.f;
        #pragma unroll
        for (int kk = 0; kk < K_ / 2; ++kk) {      // 2 neighbors per chunk
            float g[14];
            #pragma unroll
            for (int j = 0; j < 14; ++j)            // static indices (max 71)
                g[j] = sh ? f[kk*14 + j + 2] : f[kk*14 + j];
            #pragma unroll
            for (int hh = 0; hh < 2; ++hh) {
                float pre[D_];
                #pragma unroll
                for (int o = 0; o < D_; ++o) pre[o] = bias[o];
                #pragma unroll
                for (int d = 0; d < D_; ++d) {
                    const float xv = g[hh * 7 + d];
                    #pragma unroll
                    for (int o = 0; o < D_; ++o) pre[o] = fmaf(xv, w[o][d], pre[o]);
                }
                bool nz = false;
                #pragma unroll
                for (int o = 0; o < D_; ++o) nz = nz || (pre[o] != 0.f);
                cnt += nz ? 1.f : 0.f;
                #pragma unroll
                for (int o = 0; o < D_; ++o)
                    acc[o] += (pre[o] >= 0.f) ? pre[o] : NEG_SLOPE * pre[o];
            }
        }
        const float inv = 1.f / fmaxf(cnt, 1.f);
        #pragma unroll
        for (int o = 0; o < D_; ++o) h[t * D_ + o] = acc[o] * inv;

        // self candidate with this t's uniform weights; select on type match
        float ps[D_];
        #pragma unroll
        for (int o = 0; o < D_; ++o) {
            float p = bias[o];
            #pragma unroll
            for (int d = 0; d < D_; ++d) p = fmaf(x[d], w[o][d], p);
            ps[o] = (p >= 0.f) ? p : NEG_SLOPE * p;
        }
        if (tp == t) {
            #pragma unroll
            for (int o = 0; o < D_; ++o) h[T_ * D_ + o] = ps[o];
        }
    }

    // ---- epilogue: [56] x [O,56]^T + bias -> sigmoid -> wave reduce
    #pragma unroll 4
    for (int o = 0; o < O_; ++o) {
        float s = bagg[o];
        const float4* wrow = (const float4*)(Wagg + o * 56);
        #pragma unroll
        for (int q = 0; q < 14; ++q) {
            float4 w4 = wrow[q];
            s += h[4*q] * w4.x + h[4*q+1] * w4.y + h[4*q+2] * w4.z + h[4*q+3] * w4.w;
        }
        float val = active ? 1.f / (1.f + __expf(-s)) : 0.f;
        #pragma unroll
        for (int off = 32; off >= 1; off >>= 1) val += __shfl_down(val, off);
        if (tx == 0) atomicAdd(acc_out + (blockIdx.x & (NREP - 1)) * O_ + o, val);
    }
}

// ---------------- K3: sum replicas, divide by N into d_out -----------------
__global__ void k3_finish(const float* __restrict__ acc, float* __restrict__ out, float invN) {
    int o = threadIdx.x;
    if (o < O_) {
        float s = 0.f;
        #pragma unroll
        for (int rr = 0; rr < NREP; ++rr) s += acc[rr * O_ + o];
        out[o] = s * invN;
    }
}

extern "C" void kernel_launch(void* const* d_in, const int* in_sizes, int n_in,
                              void* d_out, int out_size, void* d_ws, size_t ws_size,
                              hipStream_t stream) {
    const float* xnode = (const float*)d_in[0];   // [N,D]
    const float* xhet  = (const float*)d_in[1];   // [T,N,K,D]
    const int*   types = (const int*)d_in[2];     // [N]
    const float* Wc    = (const float*)d_in[3];   // [T,D,D]
    const float* bc    = (const float*)d_in[4];   // [T,D]
    const float* Wagg  = (const float*)d_in[5];   // [O,56]
    const float* bagg  = (const float*)d_in[6];   // [O]
    float* out = (float*)d_out;

    const int N = in_sizes[2];
    float* acc_out = (float*)d_ws;                // NREP*32 floats

    const int nblk = (N + NPB - 1) / NPB;         // 1563 @ N=100000

    k0_zero<<<1, 512, 0, stream>>>(acc_out);
    k_fused<<<nblk, NPB, 0, stream>>>(xhet, xnode, types, Wc, bc, Wagg, bagg, acc_out, N);
    k3_finish<<<1, 64, 0, stream>>>(acc_out, out, 1.f / (float)N);
}

// Round 9
// 319.709 us; speedup vs baseline: 1.2700x; 1.2222x over previous
//
#include <hip/hip_runtime.h>
#include <hip/hip_bf16.h>
#include <math.h>

// Problem constants: N=100000, K=10, T=7, D=7, O=32
#define T_ 7
#define D_ 7
#define K_ 10
#define O_ 32
#define NPB 256           // nodes per block (== blockDim.x)
#define NREP 16           // replicated global accumulators (atomic spread)
#define NEG_SLOPE 0.01f

// async global->LDS DMA, 16B per lane. LDS dest: wave-uniform base, HW adds lane*16.
__device__ __forceinline__ void gl_lds16(const float4* g, float4* lds_wave_base) {
    __builtin_amdgcn_global_load_lds(
        (const __attribute__((address_space(1))) void*)g,
        (__attribute__((address_space(3))) void*)lds_wave_base,
        16, 0, 0);
}

// ---------------- K0: zero the replicated output accumulators --------------
__global__ void k0_zero(float* __restrict__ acc) {
    int i = threadIdx.x;
    if (i < NREP * O_) acc[i] = 0.f;
}

// ---------------- fused kernel --------------------------------------------
// One block = 256 nodes. Per t: barrier (prev readers done), issue ALL tile
// chunks via async global_load_lds (no VGPR round-trip, all in flight),
// barrier (drains vmcnt -> LDS visible), compute. h[56] in registers.
// Epilogue GEMM from LDS W_agg, sigmoid, wave reduce, replicated atomics.
//
// NOTE (session ledger): this structure measures 122 us for k_fused, which
// sits exactly at the machine's observed to-core read wall (~1.6 TB/s) for
// this load+compute pattern. Nine alternative structures (one-wave blocks,
// counted-vmcnt pipelines, no-LDS register streaming, NT loads, system-scope
// loads, t-split 7x-occupancy two-kernel) all landed at the same wall or
// worse; delivered BW was invariant to waves/CU (4.5-14) and to outstanding
// lines/CU (up to ~250), implying loaded latency ~2.8us (7x unloaded) --
// a request-queue/L2-miss-path saturation, not bandwidth, occupancy, or
// coalescing. This file is the best verified configuration.
__global__ __launch_bounds__(NPB) void k_fused(
    const float* __restrict__ xhet,   // [T,N,K,D]
    const float* __restrict__ xnode,  // [N,D]
    const int*   __restrict__ types,  // [N]
    const float* __restrict__ Wc,     // [T,D,D]
    const float* __restrict__ bc,     // [T,D]
    const float* __restrict__ Wagg,   // [O,56]
    const float* __restrict__ bagg,   // [O]
    float* __restrict__ acc_out,      // [NREP][O] global accumulators
    int N)
{
    __shared__ __align__(16) float tile[NPB * 70];   // 71680 B
    __shared__ float4 sW[O_ * 14];                   // 7168 B
    __shared__ float  sb[O_];
    __shared__ float  sacc[O_];
    // ~79 KB -> 2 blocks/CU (8 waves/CU)

    const int tx   = threadIdx.x;
    const int wv   = tx >> 6;         // wave id in block
    const int lane = tx & 63;
    const int nodeBase = blockIdx.x * NPB;
    const int n = nodeBase + tx;
    const bool active = (n < N);
    const int valid = min(NPB, N - nodeBase);
    const int L  = valid * 70;        // floats in this block's tile
    const int L4 = L >> 2;            // full float4 count

    // stage W_agg (1792 floats = 448 float4)
    for (int i = tx; i < O_ * 14; i += NPB) sW[i] = ((const float4*)Wagg)[i];
    if (tx < O_) { sb[tx] = bagg[tx]; sacc[tx] = 0.f; }

    // per-thread self inputs (tiny, cache-resident)
    float x[D_]; int tp = -1;
    if (active) {
        tp = types[n];
        #pragma unroll
        for (int d = 0; d < D_; ++d) x[d] = xnode[(size_t)n * D_ + d];
    } else {
        #pragma unroll
        for (int d = 0; d < D_; ++d) x[d] = 0.f;
    }

    float h[(T_ + 1) * D_];           // concat layout: h[t*7+o], self at 49..55
    #pragma unroll
    for (int j = 0; j < (T_ + 1) * D_; ++j) h[j] = 0.f;

    float4* tile4 = (float4*)tile;

    for (int t = 0; t < T_; ++t) {
        // block-uniform weights -> scalar regs
        float w[D_][D_], bias[D_];
        #pragma unroll
        for (int o = 0; o < D_; ++o) {
            bias[o] = bc[t * D_ + o];
            #pragma unroll
            for (int d = 0; d < D_; ++d) w[o][d] = Wc[(t * D_ + o) * D_ + d];
        }

        const float*  src  = xhet + ((size_t)t * N + nodeBase) * 70;
        const float4* src4 = (const float4*)src;     // 16B-aligned

        __syncthreads();   // previous iteration's readers done before overwrite

        // ---- issue ALL chunks async global->LDS (18 in flight per wave)
        // chunk j covers float4 indices [j*NPB, (j+1)*NPB); this wave's 64
        // lanes handle base+wv*64 .. base+wv*64+63, LDS dest = same indices.
        #pragma unroll
        for (int j = 0; j < 18; ++j) {               // ceil(4480/256)=18 when full
            const int i = j * NPB + wv * 64 + lane;  // == j*NPB + tx
            if (i < L4) gl_lds16(src4 + i, tile4 + j * NPB + wv * 64);
        }
        // rare scalar tail (only if L%4 != 0; impossible for even `valid`)
        for (int i = (L4 << 2) + tx; i < L; i += NPB) tile[i] = src[i];

        __syncthreads();   // drains vmcnt -> all async LDS writes visible

        if (active) {
            const float* myp = tile + tx * 70;
            float acc[D_] = {0.f, 0.f, 0.f, 0.f, 0.f, 0.f, 0.f};
            float cnt = 0.f;
            #pragma unroll
            for (int kk = 0; kk < K_ / 2; ++kk) {    // k in pairs: 14 floats = 7 float2
                float f[14];
                const float2* p2 = (const float2*)(myp + kk * 14);
                #pragma unroll
                for (int j = 0; j < 7; ++j) { float2 v = p2[j]; f[2*j] = v.x; f[2*j+1] = v.y; }
                #pragma unroll
                for (int hh = 0; hh < 2; ++hh) {
                    float pre[D_];
                    #pragma unroll
                    for (int o = 0; o < D_; ++o) pre[o] = bias[o];
                    #pragma unroll
                    for (int d = 0; d < D_; ++d) {
                        const float xv = f[hh * 7 + d];
                        #pragma unroll
                        for (int o = 0; o < D_; ++o) pre[o] = fmaf(xv, w[o][d], pre[o]);
                    }
                    bool nz = false;
                    #pragma unroll
                    for (int o = 0; o < D_; ++o) nz = nz || (pre[o] != 0.f);
                    cnt += nz ? 1.f : 0.f;
                    #pragma unroll
                    for (int o = 0; o < D_; ++o)
                        acc[o] += (pre[o] >= 0.f) ? pre[o] : NEG_SLOPE * pre[o];
                }
            }
            const float inv = 1.f / fmaxf(cnt, 1.f);
            #pragma unroll
            for (int o = 0; o < D_; ++o) h[t * D_ + o] = acc[o] * inv;

            // self candidate with this t's uniform weights; select on type match
            float ps[D_];
            #pragma unroll
            for (int o = 0; o < D_; ++o) {
                float p = bias[o];
                #pragma unroll
                for (int d = 0; d < D_; ++d) p = fmaf(x[d], w[o][d], p);
                ps[o] = (p >= 0.f) ? p : NEG_SLOPE * p;
            }
            if (tp == t) {
                #pragma unroll
                for (int o = 0; o < D_; ++o) h[T_ * D_ + o] = ps[o];
            }
        }
    }

    // ---- epilogue: [56] x [O,56]^T + bias -> sigmoid -> reduce
    #pragma unroll 4
    for (int o = 0; o < O_; ++o) {
        float s = sb[o];
        #pragma unroll
        for (int q = 0; q < 14; ++q) {
            float4 wv4 = sW[o * 14 + q];
            s += h[4*q] * wv4.x + h[4*q+1] * wv4.y + h[4*q+2] * wv4.z + h[4*q+3] * wv4.w;
        }
        float val = active ? 1.f / (1.f + __expf(-s)) : 0.f;
        #pragma unroll
        for (int off = 32; off >= 1; off >>= 1) val += __shfl_down(val, off);
        if (lane == 0) atomicAdd(&sacc[o], val);
    }
    __syncthreads();
    if (tx < O_) atomicAdd(acc_out + (blockIdx.x & (NREP - 1)) * O_ + tx, sacc[tx]);
}

// ---------------- K3: sum replicas, divide by N into d_out -----------------
__global__ void k3_finish(const float* __restrict__ acc, float* __restrict__ out, float invN) {
    int o = threadIdx.x;
    if (o < O_) {
        float s = 0.f;
        #pragma unroll
        for (int rr = 0; rr < NREP; ++rr) s += acc[rr * O_ + o];
        out[o] = s * invN;
    }
}

extern "C" void kernel_launch(void* const* d_in, const int* in_sizes, int n_in,
                              void* d_out, int out_size, void* d_ws, size_t ws_size,
                              hipStream_t stream) {
    const float* xnode = (const float*)d_in[0];   // [N,D]
    const float* xhet  = (const float*)d_in[1];   // [T,N,K,D]
    const int*   types = (const int*)d_in[2];     // [N]
    const float* Wc    = (const float*)d_in[3];   // [T,D,D]
    const float* bc    = (const float*)d_in[4];   // [T,D]
    const float* Wagg  = (const float*)d_in[5];   // [O,56]
    const float* bagg  = (const float*)d_in[6];   // [O]
    float* out = (float*)d_out;

    const int N = in_sizes[2];
    float* acc_out = (float*)d_ws;                // NREP*32 floats

    const int nblk = (N + NPB - 1) / NPB;

    k0_zero<<<1, 512, 0, stream>>>(acc_out);
    k_fused<<<nblk, NPB, 0, stream>>>(xhet, xnode, types, Wc, bc, Wagg, bagg, acc_out, N);
    k3_finish<<<1, 64, 0, stream>>>(acc_out, out, 1.f / (float)N);
}